// Round 5
// baseline (173.747 us; speedup 1.0000x reference)
//
#include <hip/hip_runtime.h>
#include <hip/hip_fp16.h>

#define CC 256
#define HH 200
#define WW 304
#define PHW 49    // 7*7
#define XT 16     // x-tile for transpose
#define NCHUNK 8  // channel chunks
#define CHC 32    // channels per chunk

struct Interp { int lo, hi; float w0, w1; };

__device__ __forceinline__ Interp axis_interp(float coord, int size) {
  float valid = (coord >= -1.0f && coord <= (float)size) ? 1.0f : 0.0f;
  float c = fminf(fmaxf(coord, 0.0f), (float)(size - 1));
  float fl = floorf(c);
  int lo = (int)fl;
  int hi = min(lo + 1, size - 1);
  float fr = c - fl;
  Interp r;
  r.lo = lo; r.hi = hi;
  r.w0 = (1.0f - fr) * valid;
  r.w1 = fr * valid;
  return r;
}

__device__ __forceinline__ float4 h4_to_f4(ushort4 u) {
  __half2 a = *(__half2*)&u.x;
  __half2 b = *(__half2*)&u.z;
  float2 fa = __half22float2(a);
  float2 fb = __half22float2(b);
  return make_float4(fa.x, fa.y, fb.x, fb.y);
}

// Deterministic spatial sort of ROIs: key = (b, y-half, x-octant); rank by
// (key, index). O(K^2) scan in one block with LDS-broadcast reads — few us.
__global__ __launch_bounds__(1024) void k_sortrois(const float* __restrict__ rois,
                                                   int K, int Bp,
                                                   int* __restrict__ perm) {
  __shared__ unsigned char keys[1024];
  int tid = threadIdx.x;
  if (K > 1024) {               // unexpected shape: identity mapping
    for (int i = tid; i < K; i += 1024) perm[i] = i;
    return;
  }
  if (tid < K) {
    const float* r = rois + (size_t)tid * 5;
    int b = (int)r[0]; b = max(0, min(Bp - 1, b));
    float cx = (r[1] + r[3]) * 0.125f;   // center * spatial_scale
    float cy = (r[2] + r[4]) * 0.125f;
    int rx = (int)(cx * (8.0f / (float)WW)); rx = max(0, min(7, rx));
    int ry = cy >= (float)(HH / 2) ? 1 : 0;
    keys[tid] = (unsigned char)((b * 2 + ry) * 8 + rx);
  }
  __syncthreads();
  if (tid < K) {
    int ki = keys[tid], c = 0;
    for (int j = 0; j < K; ++j) {
      int kj = keys[j];
      c += (kj < ki) || (kj == ki && j < tid);
    }
    perm[c] = tid;
  }
}

// NCHW fp32 -> chunked NHWC fp16: dst[((chunk*B + b)*H*W + y*W + x)*32 + c%32]
__global__ __launch_bounds__(256) void k_transpose_f16c(const float* __restrict__ src,
                                                        __half* __restrict__ dst,
                                                        int Bp) {
  __shared__ float tile[XT][CC + 4];
  int plane = blockIdx.y;              // b*HH + y
  int x0 = blockIdx.x * XT;            // WW == 19*16
  int b = plane / HH;
  int y = plane - b * HH;
  const float* sp = src + (size_t)b * CC * HH * WW + (size_t)y * WW + x0;
  int cr = threadIdx.x >> 2;           // 0..63
  int x4 = (threadIdx.x & 3) * 4;      // 0,4,8,12
#pragma unroll
  for (int pass = 0; pass < 4; ++pass) {
    int c = cr + pass * 64;
    float4 v = *(const float4*)(sp + (size_t)c * HH * WW + x4);
    tile[x4 + 0][c] = v.x;
    tile[x4 + 1][c] = v.y;
    tile[x4 + 2][c] = v.z;
    tile[x4 + 3][c] = v.w;
  }
  __syncthreads();
  int xw = threadIdx.x >> 5;           // 0..7
  int co = (threadIdx.x & 31) * 8;     // global channel 0..248
  int chunk = co >> 5;
  int cc = co & 31;
#pragma unroll
  for (int pass = 0; pass < 2; ++pass) {
    int x = xw + pass * 8;
    const float* trow = &tile[x][co];
    union { uint4 u; __half2 h[4]; } pk;
    pk.h[0] = __floats2half2_rn(trow[0], trow[1]);
    pk.h[1] = __floats2half2_rn(trow[2], trow[3]);
    pk.h[2] = __floats2half2_rn(trow[4], trow[5]);
    pk.h[3] = __floats2half2_rn(trow[6], trow[7]);
    size_t idx = (((size_t)chunk * Bp + b) * (HH * WW) +
                  (size_t)y * WW + (x0 + x)) * CHC + cc;
    *(uint4*)(dst + idx) = pk.u;
  }
}

// Grid (8*q roi-slots, NCHUNK). XCD-swizzled so each XCD owns one contiguous
// spatial bucket of sorted ROIs; per-(bucket,chunk) footprint ~2-3 MB -> L2.
// Block 512 thr, wave handles bins p = wave, wave+8, ...
// Lane roles: s=sx (lane>>5), corner sel (lane>>3)&3, l=channel-quad (lane&7).
// One wave-inst loads 2 samples x 4 corners x 32ch; bin reduced via shfl_xor.
__global__ __launch_bounds__(512, 8) void k_gather(const __half* __restrict__ feat,
                                                   const float* __restrict__ rois,
                                                   const int* __restrict__ perm,
                                                   float* __restrict__ out,
                                                   int K, int Bp) {
  __shared__ float lds[PHW][CHC + 1];
  int q = gridDim.x >> 3;
  int bx = blockIdx.x;
  int slot = (bx & 7) * q + (bx >> 3);
  if (slot >= K) return;
  int k = perm[slot];
  int chunk = blockIdx.y;

  const float* r = rois + (size_t)k * 5;
  int b = (int)r[0];
  float x1 = r[1] * 0.25f, y1 = r[2] * 0.25f;
  float x2 = r[3] * 0.25f, y2 = r[4] * 0.25f;
  float bin_w = fmaxf(x2 - x1, 1.0f) * (1.0f / 7.0f);
  float bin_h = fmaxf(y2 - y1, 1.0f) * (1.0f / 7.0f);

  int wave = threadIdx.x >> 6;         // 0..7
  int lane = threadIdx.x & 63;
  int s = lane >> 5;                   // sx sample index
  int c4 = (lane >> 3) & 3;            // corner: bit1=cy_sel, bit0=cx_sel
  int cy_sel = c4 >> 1, cx_sel = c4 & 1;
  int l = lane & 7;                    // channel quad within chunk

  const __half* fb = feat + ((size_t)chunk * Bp + b) * (size_t)(HH * WW) * CHC +
                     (size_t)l * 4;

  for (int p = wave; p < PHW; p += 8) {
    int ph = p / 7;
    int pw = p - ph * 7;
    float xx = x1 + ((float)(2 * pw + s) + 0.5f) * 0.5f * bin_w;
    Interp ix = axis_interp(xx, WW);
    int xi = cx_sel ? ix.hi : ix.lo;
    float wx = cx_sel ? ix.w1 : ix.w0;
    float4 a = make_float4(0.f, 0.f, 0.f, 0.f);
#pragma unroll
    for (int sy = 0; sy < 2; ++sy) {
      float yy = y1 + ((float)(2 * ph + sy) + 0.5f) * 0.5f * bin_h;
      Interp iy = axis_interp(yy, HH);
      int yi = cy_sel ? iy.hi : iy.lo;
      float wy = cy_sel ? iy.w1 : iy.w0;
      ushort4 u = *(const ushort4*)(fb + ((size_t)yi * WW + xi) * CHC);
      float4 v = h4_to_f4(u);
      float w = wy * wx;
      a.x += w * v.x; a.y += w * v.y; a.z += w * v.z; a.w += w * v.w;
    }
    // reduce over cx (xor 8), cy (xor 16), sx (xor 32)
#pragma unroll
    for (int m = 8; m <= 32; m <<= 1) {
      a.x += __shfl_xor(a.x, m);
      a.y += __shfl_xor(a.y, m);
      a.z += __shfl_xor(a.z, m);
      a.w += __shfl_xor(a.w, m);
    }
    if (lane < 8) {
      lds[p][l * 4 + 0] = a.x * 0.25f;
      lds[p][l * 4 + 1] = a.y * 0.25f;
      lds[p][l * 4 + 2] = a.z * 0.25f;
      lds[p][l * 4 + 3] = a.w * 0.25f;
    }
  }
  __syncthreads();

  // Contiguous coalesced write: out[k][chunk*32+cc][p], linear in i.
  float* outk = out + (size_t)k * CC * PHW + (size_t)chunk * CHC * PHW;
  for (int i = threadIdx.x; i < CHC * PHW; i += 512) {
    int cc = i / PHW;
    int p = i - cc * PHW;
    outk[i] = lds[p][cc];
  }
}

// Fallback if workspace too small: one thread per output element, NCHW fp32.
__global__ __launch_bounds__(256) void k_roialign_direct(const float* __restrict__ fe,
                                                         const float* __restrict__ rois,
                                                         float* __restrict__ out,
                                                         int total) {
  int idx = blockIdx.x * 256 + threadIdx.x;
  if (idx >= total) return;
  int pw = idx % 7;
  int t = idx / 7;
  int ph = t % 7; t /= 7;
  int c = t % CC;
  int k = t / CC;
  const float* r = rois + (size_t)k * 5;
  int b = (int)r[0];
  float x1 = r[1] * 0.25f, y1 = r[2] * 0.25f;
  float x2 = r[3] * 0.25f, y2 = r[4] * 0.25f;
  float bin_w = fmaxf(x2 - x1, 1.0f) * (1.0f / 7.0f);
  float bin_h = fmaxf(y2 - y1, 1.0f) * (1.0f / 7.0f);
  const float* base = fe + ((size_t)b * CC + c) * HH * WW;
  float acc = 0.f;
#pragma unroll
  for (int sy = 0; sy < 2; ++sy) {
    float yy = y1 + ((float)(2 * ph + sy) + 0.5f) * 0.5f * bin_h;
    Interp iy = axis_interp(yy, HH);
#pragma unroll
    for (int sx = 0; sx < 2; ++sx) {
      float xx = x1 + ((float)(2 * pw + sx) + 0.5f) * 0.5f * bin_w;
      Interp ix = axis_interp(xx, WW);
      float v00 = base[(size_t)iy.lo * WW + ix.lo];
      float v01 = base[(size_t)iy.lo * WW + ix.hi];
      float v10 = base[(size_t)iy.hi * WW + ix.lo];
      float v11 = base[(size_t)iy.hi * WW + ix.hi];
      acc += iy.w0 * ix.w0 * v00 + iy.w0 * ix.w1 * v01 +
             iy.w1 * ix.w0 * v10 + iy.w1 * ix.w1 * v11;
    }
  }
  out[idx] = acc * 0.25f;
}

extern "C" void kernel_launch(void* const* d_in, const int* in_sizes, int n_in,
                              void* d_out, int out_size, void* d_ws, size_t ws_size,
                              hipStream_t stream) {
  const float* features = (const float*)d_in[0];
  const float* rois = (const float*)d_in[1];
  float* out = (float*)d_out;
  int B = in_sizes[0] / (CC * HH * WW);
  int K = in_sizes[1] / 5;
  size_t feat_bytes = (size_t)B * HH * WW * CC * sizeof(__half);
  size_t perm_bytes = (size_t)((K + 7) & ~7) * sizeof(int);
  if (ws_size >= feat_bytes + perm_bytes && K <= 1024) {
    __half* feat16 = (__half*)d_ws;
    int* perm = (int*)((char*)d_ws + feat_bytes);
    k_sortrois<<<1, 1024, 0, stream>>>(rois, K, B, perm);
    dim3 tg(WW / XT, B * HH);          // 19 x 400
    k_transpose_f16c<<<tg, 256, 0, stream>>>(features, feat16, B);
    int q = (K + 7) / 8;
    dim3 gg(8 * q, NCHUNK);
    k_gather<<<gg, 512, 0, stream>>>(feat16, rois, perm, out, K, B);
  } else {
    int total = K * CC * PHW;
    k_roialign_direct<<<(total + 255) / 256, 256, 0, stream>>>(features, rois, out, total);
  }
}

// Round 6
// 91.594 us; speedup vs baseline: 1.8969x; 1.8969x over previous
//
#include <hip/hip_runtime.h>
#include <hip/hip_fp16.h>

#define CC 256
#define HH 200
#define WW 304
#define PHW 49    // 7*7
#define XT 16     // x-tile for transpose
#define NCHUNK 2  // channel chunks
#define CHC 128   // channels per chunk
#define SSTR 132  // stage row stride (floats)

struct Interp { int lo, hi; float w0, w1; };

__device__ __forceinline__ Interp axis_interp(float coord, int size) {
  float valid = (coord >= -1.0f && coord <= (float)size) ? 1.0f : 0.0f;
  float c = fminf(fmaxf(coord, 0.0f), (float)(size - 1));
  float fl = floorf(c);
  int lo = (int)fl;
  int hi = min(lo + 1, size - 1);
  float fr = c - fl;
  Interp r;
  r.lo = lo; r.hi = hi;
  r.w0 = (1.0f - fr) * valid;
  r.w1 = fr * valid;
  return r;
}

__device__ __forceinline__ float4 h4_to_f4(ushort4 u) {
  __half2 a = *(__half2*)&u.x;
  __half2 b = *(__half2*)&u.z;
  float2 fa = __half22float2(a);
  float2 fb = __half22float2(b);
  return make_float4(fa.x, fa.y, fb.x, fb.y);
}

// Deterministic stable bucket sort via per-wave ballot ranking. ~2-3 us.
// key = (b, y-half, x-octant) -> 32 buckets; rank = stable (key, index).
__global__ __launch_bounds__(1024) void k_sortrois(const float* __restrict__ rois,
                                                   int K, int Bp,
                                                   int* __restrict__ perm) {
  __shared__ int whist[16][32];
  __shared__ int keytot[32];
  __shared__ int keybase[32];
  int tid = threadIdx.x;
  if (K > 1024) {               // unexpected shape: identity mapping
    for (int i = tid; i < K; i += 1024) perm[i] = i;
    return;
  }
  int wave = tid >> 6, lane = tid & 63;
  bool active = tid < K;
  int key = 63;                 // inactive sentinel outside 0..31
  if (active) {
    const float* r = rois + (size_t)tid * 5;
    int b = (int)r[0];
    float cx = (r[1] + r[3]) * 0.125f;   // center * spatial_scale
    float cy = (r[2] + r[4]) * 0.125f;
    int rx = (int)(cx * (8.0f / (float)WW)); rx = max(0, min(7, rx));
    int ry = cy >= (float)(HH / 2) ? 1 : 0;
    key = (((b & 1) * 2 + ry) * 8 + rx) & 31;
  }
  if (tid < 512) ((int*)whist)[tid] = 0;
  __syncthreads();
  unsigned long long m = ~0ull;
#pragma unroll
  for (int bit = 0; bit < 6; ++bit) {
    unsigned long long bb = __ballot((key >> bit) & 1);
    m &= ((key >> bit) & 1) ? bb : ~bb;
  }
  unsigned long long below = m & ((1ull << lane) - 1ull);
  int rank = __popcll(below);
  if (active && below == 0ull) whist[wave][key] = __popcll(m);
  __syncthreads();
  if (tid < 32) {
    int total = 0;
    for (int w = 0; w < 16; ++w) {
      int t = whist[w][tid];
      whist[w][tid] = total;     // exclusive prefix within key
      total += t;
    }
    keytot[tid] = total;
  }
  __syncthreads();
  if (tid == 0) {
    int base = 0;
    for (int k2 = 0; k2 < 32; ++k2) { keybase[k2] = base; base += keytot[k2]; }
  }
  __syncthreads();
  if (active) perm[keybase[key] + whist[wave][key] + rank] = tid;
}

// NCHW fp32 -> chunked NHWC fp16: dst[((chunk*B+b)*H*W + y*W + x)*128 + c%128]
__global__ __launch_bounds__(256) void k_transpose_f16c(const float* __restrict__ src,
                                                        __half* __restrict__ dst,
                                                        int Bp) {
  __shared__ float tile[XT][CC + 4];
  int plane = blockIdx.y;              // b*HH + y
  int x0 = blockIdx.x * XT;            // WW == 19*16
  int b = plane / HH;
  int y = plane - b * HH;
  const float* sp = src + (size_t)b * CC * HH * WW + (size_t)y * WW + x0;
  int cr = threadIdx.x >> 2;           // 0..63
  int x4 = (threadIdx.x & 3) * 4;      // 0,4,8,12
#pragma unroll
  for (int pass = 0; pass < 4; ++pass) {
    int c = cr + pass * 64;
    float4 v = *(const float4*)(sp + (size_t)c * HH * WW + x4);
    tile[x4 + 0][c] = v.x;
    tile[x4 + 1][c] = v.y;
    tile[x4 + 2][c] = v.z;
    tile[x4 + 3][c] = v.w;
  }
  __syncthreads();
  int xw = threadIdx.x >> 5;           // 0..7
  int co = (threadIdx.x & 31) * 8;     // global channel 0..248
  int chunk = co >> 7;
  int cc = co & 127;
#pragma unroll
  for (int pass = 0; pass < 2; ++pass) {
    int x = xw + pass * 8;
    const float* trow = &tile[x][co];
    union { uint4 u; __half2 h[4]; } pk;
    pk.h[0] = __floats2half2_rn(trow[0], trow[1]);
    pk.h[1] = __floats2half2_rn(trow[2], trow[3]);
    pk.h[2] = __floats2half2_rn(trow[4], trow[5]);
    pk.h[3] = __floats2half2_rn(trow[6], trow[7]);
    size_t idx = (((size_t)chunk * Bp + b) * (size_t)(HH * WW) +
                  (size_t)y * WW + (x0 + x)) * CHC + cc;
    *(uint4*)(dst + idx) = pk.u;
  }
}

// Grid (8*q slots, NCHUNK), XCD-swizzled sorted slots -> per-XCD L2 locality.
// Block 512 thr / 8 waves per (ROI, 128-ch chunk); wave handles bins p=wave+8i.
// Lane: xsel = lane>>5 (x-corner; the two half-wave 256B segments are adjacent
// pixels -> one 512B contiguous wave-load), cq = lane&31 (4 channels).
// Per-ROI interp tables precomputed in LDS; one shfl_xor(32) reduce per bin.
__global__ __launch_bounds__(512, 8) void k_gather(const __half* __restrict__ feat,
                                                   const float* __restrict__ rois,
                                                   const int* __restrict__ perm,
                                                   float* __restrict__ out,
                                                   int K, int Bp) {
  __shared__ float stage[PHW][SSTR];
  __shared__ float xw2[14][2], yw2[14][2];
  __shared__ int xi2[14][2], yi2[14][2];
  int q = gridDim.x >> 3;
  int bx = blockIdx.x;
  int slot = (bx & 7) * q + (bx >> 3);
  if (slot >= K) return;
  int k = perm[slot];
  int chunk = blockIdx.y;

  const float* r = rois + (size_t)k * 5;
  int b = (int)r[0];
  float x1 = r[1] * 0.25f, y1 = r[2] * 0.25f;
  float x2 = r[3] * 0.25f, y2 = r[4] * 0.25f;
  float bin_w = fmaxf(x2 - x1, 1.0f) * (1.0f / 7.0f);
  float bin_h = fmaxf(y2 - y1, 1.0f) * (1.0f / 7.0f);

  int tid = threadIdx.x;
  if (tid < 32) {                      // build interp tables: x: 0..13, y: 16..29
    int axis = tid >> 4;
    int j = tid & 15;
    if (j < 14) {
      float start = axis ? y1 : x1;
      float binsz = axis ? bin_h : bin_w;
      int size = axis ? HH : WW;
      float coord = start + ((float)j + 0.5f) * 0.5f * binsz;
      Interp ii = axis_interp(coord, size);
      if (axis) { yi2[j][0] = ii.lo; yi2[j][1] = ii.hi; yw2[j][0] = ii.w0; yw2[j][1] = ii.w1; }
      else      { xi2[j][0] = ii.lo; xi2[j][1] = ii.hi; xw2[j][0] = ii.w0; xw2[j][1] = ii.w1; }
    }
  }
  __syncthreads();

  int wave = tid >> 6;                 // 0..7
  int lane = tid & 63;
  int xsel = lane >> 5;                // x-corner select
  int cq = lane & 31;                  // channel quad within chunk
  const __half* fb = feat + ((size_t)chunk * Bp + b) * (size_t)(HH * WW) * CHC +
                     (size_t)cq * 4;

  for (int p = wave; p < PHW; p += 8) {
    int ph = p / 7;
    int pw = p - ph * 7;
    int jx0 = 2 * pw, jy0 = 2 * ph;
    float ax = 0.f, ay = 0.f, az = 0.f, aw = 0.f;
#pragma unroll
    for (int sx = 0; sx < 2; ++sx) {
      int xi = xi2[jx0 + sx][xsel];
      float wx = xw2[jx0 + sx][xsel];
#pragma unroll
      for (int sy = 0; sy < 2; ++sy) {
        int jy = jy0 + sy;
        int ylo = yi2[jy][0], yhi = yi2[jy][1];
        float w0 = yw2[jy][0] * wx, w1 = yw2[jy][1] * wx;
        ushort4 u0 = *(const ushort4*)(fb + ((size_t)ylo * WW + xi) * CHC);
        ushort4 u1 = *(const ushort4*)(fb + ((size_t)yhi * WW + xi) * CHC);
        float4 v0 = h4_to_f4(u0), v1 = h4_to_f4(u1);
        ax += w0 * v0.x + w1 * v1.x;
        ay += w0 * v0.y + w1 * v1.y;
        az += w0 * v0.z + w1 * v1.z;
        aw += w0 * v0.w + w1 * v1.w;
      }
    }
    ax += __shfl_xor(ax, 32);
    ay += __shfl_xor(ay, 32);
    az += __shfl_xor(az, 32);
    aw += __shfl_xor(aw, 32);
    if (lane < 32) {
      float* s = &stage[p][cq * 4];
      s[0] = ax * 0.25f;
      s[1] = ay * 0.25f;
      s[2] = az * 0.25f;
      s[3] = aw * 0.25f;
    }
  }
  __syncthreads();

  // Contiguous coalesced write: out[k][chunk*128+cc][p], linear in i.
  float* outk = out + (size_t)k * CC * PHW + (size_t)chunk * CHC * PHW;
  for (int i = tid; i < CHC * PHW; i += 512) {
    int cc = i / PHW;
    int p = i - cc * PHW;
    outk[i] = stage[p][cc];
  }
}

// Fallback if workspace too small: one thread per output element, NCHW fp32.
__global__ __launch_bounds__(256) void k_roialign_direct(const float* __restrict__ fe,
                                                         const float* __restrict__ rois,
                                                         float* __restrict__ out,
                                                         int total) {
  int idx = blockIdx.x * 256 + threadIdx.x;
  if (idx >= total) return;
  int pw = idx % 7;
  int t = idx / 7;
  int ph = t % 7; t /= 7;
  int c = t % CC;
  int k = t / CC;
  const float* r = rois + (size_t)k * 5;
  int b = (int)r[0];
  float x1 = r[1] * 0.25f, y1 = r[2] * 0.25f;
  float x2 = r[3] * 0.25f, y2 = r[4] * 0.25f;
  float bin_w = fmaxf(x2 - x1, 1.0f) * (1.0f / 7.0f);
  float bin_h = fmaxf(y2 - y1, 1.0f) * (1.0f / 7.0f);
  const float* base = fe + ((size_t)b * CC + c) * HH * WW;
  float acc = 0.f;
#pragma unroll
  for (int sy = 0; sy < 2; ++sy) {
    float yy = y1 + ((float)(2 * ph + sy) + 0.5f) * 0.5f * bin_h;
    Interp iy = axis_interp(yy, HH);
#pragma unroll
    for (int sx = 0; sx < 2; ++sx) {
      float xx = x1 + ((float)(2 * pw + sx) + 0.5f) * 0.5f * bin_w;
      Interp ix = axis_interp(xx, WW);
      float v00 = base[(size_t)iy.lo * WW + ix.lo];
      float v01 = base[(size_t)iy.lo * WW + ix.hi];
      float v10 = base[(size_t)iy.hi * WW + ix.lo];
      float v11 = base[(size_t)iy.hi * WW + ix.hi];
      acc += iy.w0 * ix.w0 * v00 + iy.w0 * ix.w1 * v01 +
             iy.w1 * ix.w0 * v10 + iy.w1 * ix.w1 * v11;
    }
  }
  out[idx] = acc * 0.25f;
}

extern "C" void kernel_launch(void* const* d_in, const int* in_sizes, int n_in,
                              void* d_out, int out_size, void* d_ws, size_t ws_size,
                              hipStream_t stream) {
  const float* features = (const float*)d_in[0];
  const float* rois = (const float*)d_in[1];
  float* out = (float*)d_out;
  int B = in_sizes[0] / (CC * HH * WW);
  int K = in_sizes[1] / 5;
  size_t feat_bytes = (size_t)B * HH * WW * CC * sizeof(__half);
  size_t perm_bytes = (size_t)((K + 7) & ~7) * sizeof(int);
  if (ws_size >= feat_bytes + perm_bytes && K <= 1024) {
    __half* feat16 = (__half*)d_ws;
    int* perm = (int*)((char*)d_ws + feat_bytes);
    k_sortrois<<<1, 1024, 0, stream>>>(rois, K, B, perm);
    dim3 tg(WW / XT, B * HH);          // 19 x 400
    k_transpose_f16c<<<tg, 256, 0, stream>>>(features, feat16, B);
    int q = (K + 7) / 8;
    dim3 gg(8 * q, NCHUNK);
    k_gather<<<gg, 512, 0, stream>>>(feat16, rois, perm, out, K, B);
  } else {
    int total = K * CC * PHW;
    k_roialign_direct<<<(total + 255) / 256, 256, 0, stream>>>(features, rois, out, total);
  }
}

// Round 7
// 91.384 us; speedup vs baseline: 1.9013x; 1.0023x over previous
//
#include <hip/hip_runtime.h>
#include <hip/hip_fp16.h>

#define CC 256
#define HH 200
#define WW 304
#define PHW 49    // 7*7
#define XT 16     // x-tile for transpose
#define NCHUNK 2  // channel chunks
#define CHC 128   // channels per chunk
#define SSTR 132  // stage row stride (floats)

struct Interp { int lo, hi; float w0, w1; };

__device__ __forceinline__ Interp axis_interp(float coord, int size) {
  float valid = (coord >= -1.0f && coord <= (float)size) ? 1.0f : 0.0f;
  float c = fminf(fmaxf(coord, 0.0f), (float)(size - 1));
  float fl = floorf(c);
  int lo = (int)fl;
  int hi = min(lo + 1, size - 1);
  float fr = c - fl;
  Interp r;
  r.lo = lo; r.hi = hi;
  r.w0 = (1.0f - fr) * valid;
  r.w1 = fr * valid;
  return r;
}

__device__ __forceinline__ float4 h4_to_f4(ushort4 u) {
  __half2 a = *(__half2*)&u.x;
  __half2 b = *(__half2*)&u.z;
  float2 fa = __half22float2(a);
  float2 fb = __half22float2(b);
  return make_float4(fa.x, fa.y, fb.x, fb.y);
}

// Deterministic stable bucket sort via per-wave ballot ranking. ~2-3 us.
__global__ __launch_bounds__(1024) void k_sortrois(const float* __restrict__ rois,
                                                   int K, int Bp,
                                                   int* __restrict__ perm) {
  __shared__ int whist[16][32];
  __shared__ int keytot[32];
  __shared__ int keybase[32];
  int tid = threadIdx.x;
  if (K > 1024) {               // unexpected shape: identity mapping
    for (int i = tid; i < K; i += 1024) perm[i] = i;
    return;
  }
  int wave = tid >> 6, lane = tid & 63;
  bool active = tid < K;
  int key = 63;                 // inactive sentinel outside 0..31
  if (active) {
    const float* r = rois + (size_t)tid * 5;
    int b = (int)r[0];
    float cx = (r[1] + r[3]) * 0.125f;   // center * spatial_scale
    float cy = (r[2] + r[4]) * 0.125f;
    int rx = (int)(cx * (8.0f / (float)WW)); rx = max(0, min(7, rx));
    int ry = cy >= (float)(HH / 2) ? 1 : 0;
    key = (((b & 1) * 2 + ry) * 8 + rx) & 31;
  }
  if (tid < 512) ((int*)whist)[tid] = 0;
  __syncthreads();
  unsigned long long m = ~0ull;
#pragma unroll
  for (int bit = 0; bit < 6; ++bit) {
    unsigned long long bb = __ballot((key >> bit) & 1);
    m &= ((key >> bit) & 1) ? bb : ~bb;
  }
  unsigned long long below = m & ((1ull << lane) - 1ull);
  int rank = __popcll(below);
  if (active && below == 0ull) whist[wave][key] = __popcll(m);
  __syncthreads();
  if (tid < 32) {
    int total = 0;
    for (int w = 0; w < 16; ++w) {
      int t = whist[w][tid];
      whist[w][tid] = total;     // exclusive prefix within key
      total += t;
    }
    keytot[tid] = total;
  }
  __syncthreads();
  if (tid == 0) {
    int base = 0;
    for (int k2 = 0; k2 < 32; ++k2) { keybase[k2] = base; base += keytot[k2]; }
  }
  __syncthreads();
  if (active) perm[keybase[key] + whist[wave][key] + rank] = tid;
}

// NCHW fp32 -> chunked NHWC fp16: dst[((chunk*B+b)*H*W + y*W + x)*128 + c%128]
__global__ __launch_bounds__(256) void k_transpose_f16c(const float* __restrict__ src,
                                                        __half* __restrict__ dst,
                                                        int Bp) {
  __shared__ float tile[XT][CC + 4];
  int plane = blockIdx.y;              // b*HH + y
  int x0 = blockIdx.x * XT;            // WW == 19*16
  int b = plane / HH;
  int y = plane - b * HH;
  const float* sp = src + (size_t)b * CC * HH * WW + (size_t)y * WW + x0;
  int cr = threadIdx.x >> 2;           // 0..63
  int x4 = (threadIdx.x & 3) * 4;      // 0,4,8,12
#pragma unroll
  for (int pass = 0; pass < 4; ++pass) {
    int c = cr + pass * 64;
    float4 v = *(const float4*)(sp + (size_t)c * HH * WW + x4);
    tile[x4 + 0][c] = v.x;
    tile[x4 + 1][c] = v.y;
    tile[x4 + 2][c] = v.z;
    tile[x4 + 3][c] = v.w;
  }
  __syncthreads();
  int xw = threadIdx.x >> 5;           // 0..7
  int co = (threadIdx.x & 31) * 8;     // global channel 0..248
  int chunk = co >> 7;
  int cc = co & 127;
#pragma unroll
  for (int pass = 0; pass < 2; ++pass) {
    int x = xw + pass * 8;
    const float* trow = &tile[x][co];
    union { uint4 u; __half2 h[4]; } pk;
    pk.h[0] = __floats2half2_rn(trow[0], trow[1]);
    pk.h[1] = __floats2half2_rn(trow[2], trow[3]);
    pk.h[2] = __floats2half2_rn(trow[4], trow[5]);
    pk.h[3] = __floats2half2_rn(trow[6], trow[7]);
    size_t idx = (((size_t)chunk * Bp + b) * (size_t)(HH * WW) +
                  (size_t)y * WW + (x0 + x)) * CHC + cc;
    *(uint4*)(dst + idx) = pk.u;
  }
}

// Grid (8*q slots, NCHUNK), XCD-swizzled sorted slots -> per-XCD L2 locality.
// Gather diet: scalar (saddr) feature base + premultiplied byte-offset tables
// (one v_add per load), packed-fp16 y-interp per sample, fp32 cross-sample acc.
__global__ __launch_bounds__(512, 8) void k_gather(const __half* __restrict__ feat,
                                                   const float* __restrict__ rois,
                                                   const int* __restrict__ perm,
                                                   float* __restrict__ out,
                                                   int K, int Bp) {
  __shared__ float stage[PHW][SSTR];
  __shared__ int   xoff[14][2];   // xi * CHC*2  (bytes)
  __shared__ float xwgt[14][2];   // wx * 0.25 folded
  __shared__ int2  yoff[14];      // (ylo, yhi) * WW*CHC*2 (bytes)
  __shared__ float2 ywgt[14];     // (w0, w1)
  int q = gridDim.x >> 3;
  int bx = blockIdx.x;
  int slot = (bx & 7) * q + (bx >> 3);
  if (slot >= K) return;
  int k = perm[slot];
  int chunk = blockIdx.y;

  const float* r = rois + (size_t)k * 5;
  int b = __builtin_amdgcn_readfirstlane((int)r[0]);
  float x1 = r[1] * 0.25f, y1 = r[2] * 0.25f;
  float x2 = r[3] * 0.25f, y2 = r[4] * 0.25f;
  float bin_w = fmaxf(x2 - x1, 1.0f) * (1.0f / 7.0f);
  float bin_h = fmaxf(y2 - y1, 1.0f) * (1.0f / 7.0f);

  int tid = threadIdx.x;
  if (tid < 32) {                 // interp tables: x on tid 0..13, y on 16..29
    int axis = tid >> 4;
    int j = tid & 15;
    if (j < 14) {
      float start = axis ? y1 : x1;
      float binsz = axis ? bin_h : bin_w;
      int size = axis ? HH : WW;
      float coord = start + ((float)j + 0.5f) * 0.5f * binsz;
      Interp ii = axis_interp(coord, size);
      if (axis) {
        yoff[j] = make_int2(ii.lo * (WW * CHC * 2), ii.hi * (WW * CHC * 2));
        ywgt[j] = make_float2(ii.w0, ii.w1);
      } else {
        xoff[j][0] = ii.lo * (CHC * 2);
        xoff[j][1] = ii.hi * (CHC * 2);
        xwgt[j][0] = ii.w0 * 0.25f;
        xwgt[j][1] = ii.w1 * 0.25f;
      }
    }
  }
  __syncthreads();

  int wave = tid >> 6;            // 0..7
  int lane = tid & 63;
  int xsel = lane >> 5;           // x-corner select (half-wave)
  int cq = lane & 31;             // channel quad within chunk
  const char* fb = (const char*)(feat +
      ((size_t)chunk * Bp + b) * (size_t)(HH * WW) * CHC);
  int laneByte = cq * 8;          // ushort4 = 8 B

  for (int p = wave; p < PHW; p += 8) {
    int ph = p / 7;
    int pw = p - ph * 7;
    int jx0 = 2 * pw, jy0 = 2 * ph;
    int2 yo0 = yoff[jy0], yo1 = yoff[jy0 + 1];
    float2 yw0 = ywgt[jy0], yw1 = ywgt[jy0 + 1];
    __half2 w00 = __float2half2_rn(yw0.x), w01 = __float2half2_rn(yw0.y);
    __half2 w10 = __float2half2_rn(yw1.x), w11 = __float2half2_rn(yw1.y);
    float ax = 0.f, ay = 0.f, az = 0.f, aw = 0.f;
#pragma unroll
    for (int sx = 0; sx < 2; ++sx) {
      int xo = xoff[jx0 + sx][xsel] + laneByte;
      float wx = xwgt[jx0 + sx][xsel];
#pragma unroll
      for (int sy = 0; sy < 2; ++sy) {
        const __half2 wlo = sy ? w10 : w00;
        const __half2 whi = sy ? w11 : w01;
        int2 yo = sy ? yo1 : yo0;
        ushort4 u0 = *(const ushort4*)(fb + (yo.x + xo));
        ushort4 u1 = *(const ushort4*)(fb + (yo.y + xo));
        __half2 t0 = __hfma2(*(__half2*)&u1.x, whi, __hmul2(*(__half2*)&u0.x, wlo));
        __half2 t1 = __hfma2(*(__half2*)&u1.z, whi, __hmul2(*(__half2*)&u0.z, wlo));
        float2 f0 = __half22float2(t0);
        float2 f1 = __half22float2(t1);
        ax += wx * f0.x; ay += wx * f0.y;
        az += wx * f1.x; aw += wx * f1.y;
      }
    }
    ax += __shfl_xor(ax, 32);
    ay += __shfl_xor(ay, 32);
    az += __shfl_xor(az, 32);
    aw += __shfl_xor(aw, 32);
    if (lane < 32) {
      float* s = &stage[p][cq * 4];
      s[0] = ax; s[1] = ay; s[2] = az; s[3] = aw;
    }
  }
  __syncthreads();

  // Contiguous coalesced write: out[k][chunk*128+cc][p], linear in i.
  float* outk = out + (size_t)k * CC * PHW + (size_t)chunk * CHC * PHW;
  for (int i = tid; i < CHC * PHW; i += 512) {
    int cc = i / PHW;
    int p = i - cc * PHW;
    outk[i] = stage[p][cc];
  }
}

// Fallback if workspace too small: one thread per output element, NCHW fp32.
__global__ __launch_bounds__(256) void k_roialign_direct(const float* __restrict__ fe,
                                                         const float* __restrict__ rois,
                                                         float* __restrict__ out,
                                                         int total) {
  int idx = blockIdx.x * 256 + threadIdx.x;
  if (idx >= total) return;
  int pw = idx % 7;
  int t = idx / 7;
  int ph = t % 7; t /= 7;
  int c = t % CC;
  int k = t / CC;
  const float* r = rois + (size_t)k * 5;
  int b = (int)r[0];
  float x1 = r[1] * 0.25f, y1 = r[2] * 0.25f;
  float x2 = r[3] * 0.25f, y2 = r[4] * 0.25f;
  float bin_w = fmaxf(x2 - x1, 1.0f) * (1.0f / 7.0f);
  float bin_h = fmaxf(y2 - y1, 1.0f) * (1.0f / 7.0f);
  const float* base = fe + ((size_t)b * CC + c) * HH * WW;
  float acc = 0.f;
#pragma unroll
  for (int sy = 0; sy < 2; ++sy) {
    float yy = y1 + ((float)(2 * ph + sy) + 0.5f) * 0.5f * bin_h;
    Interp iy = axis_interp(yy, HH);
#pragma unroll
    for (int sx = 0; sx < 2; ++sx) {
      float xx = x1 + ((float)(2 * pw + sx) + 0.5f) * 0.5f * bin_w;
      Interp ix = axis_interp(xx, WW);
      float v00 = base[(size_t)iy.lo * WW + ix.lo];
      float v01 = base[(size_t)iy.lo * WW + ix.hi];
      float v10 = base[(size_t)iy.hi * WW + ix.lo];
      float v11 = base[(size_t)iy.hi * WW + ix.hi];
      acc += iy.w0 * ix.w0 * v00 + iy.w0 * ix.w1 * v01 +
             iy.w1 * ix.w0 * v10 + iy.w1 * ix.w1 * v11;
    }
  }
  out[idx] = acc * 0.25f;
}

extern "C" void kernel_launch(void* const* d_in, const int* in_sizes, int n_in,
                              void* d_out, int out_size, void* d_ws, size_t ws_size,
                              hipStream_t stream) {
  const float* features = (const float*)d_in[0];
  const float* rois = (const float*)d_in[1];
  float* out = (float*)d_out;
  int B = in_sizes[0] / (CC * HH * WW);
  int K = in_sizes[1] / 5;
  size_t feat_bytes = (size_t)B * HH * WW * CC * sizeof(__half);
  size_t perm_bytes = (size_t)((K + 7) & ~7) * sizeof(int);
  if (ws_size >= feat_bytes + perm_bytes && K <= 1024) {
    __half* feat16 = (__half*)d_ws;
    int* perm = (int*)((char*)d_ws + feat_bytes);
    k_sortrois<<<1, 1024, 0, stream>>>(rois, K, B, perm);
    dim3 tg(WW / XT, B * HH);          // 19 x 400
    k_transpose_f16c<<<tg, 256, 0, stream>>>(features, feat16, B);
    int q = (K + 7) / 8;
    dim3 gg(8 * q, NCHUNK);
    k_gather<<<gg, 512, 0, stream>>>(feat16, rois, perm, out, K, B);
  } else {
    int total = K * CC * PHW;
    k_roialign_direct<<<(total + 255) / 256, 256, 0, stream>>>(features, rois, out, total);
  }
}